// Round 7
// baseline (199.362 us; speedup 1.0000x reference)
//
#include <hip/hip_runtime.h>

// ---------------------------------------------------------------------------
// GCN 2-layer forward on MI355X.
//   memset(deg,cursor)=0
//   k_degree: deg[dst]++                         (int atomics)
//   k_scan:   rowptr = exscan(deg) + dinv=rsqrt(deg+1)   (parallel, 1 block)
//   k_fill:   col[rowptr[dst]+pos++] = src       (CSR by dst)
//   k_pack_w1/w2: W -> MFMA B-fragment f16 (W2 padded to 48)
//   k_gemm1:  h1 = f16(x) @ W1   (LDS-staged, coalesced, ds_read_b128 frags)
//   k_agg1:   hp = packA(relu(Ahat*h1 + b1))  (8 gathers in flight per wave)
//   k_gemm2:  g = hp @ W2  (48 cols, col47 zero)
//   k_agg2:   out = log_softmax(Ahat*g + b2)  (unroll 8, L2-resident g)
// ---------------------------------------------------------------------------

typedef _Float16 f16;
typedef _Float16 f16x8 __attribute__((ext_vector_type(8)));
typedef _Float16 f16x4 __attribute__((ext_vector_type(4)));
typedef float f32x4 __attribute__((ext_vector_type(4)));

#define N_NODES 40000
#define N_EDGES 640000
#define D_IN 512
#define D_HID 256
#define D_OUT 47
#define D_OUT_PAD 48

// ---------------- CSR build ----------------

__global__ void k_degree(const int* __restrict__ eidx, int* __restrict__ deg) {
    int e = blockIdx.x * blockDim.x + threadIdx.x;
    if (e < N_EDGES) atomicAdd(&deg[eidx[N_EDGES + e]], 1);
}

// Parallel single-block scan: 1024 threads x 40 elems; fused dinv.
__global__ __launch_bounds__(1024) void k_scan(const int* __restrict__ deg,
                                               int* __restrict__ rowptr,
                                               float* __restrict__ dinv) {
    __shared__ int wsum[16];
    const int S = 40;
    int t = threadIdx.x;
    int lane = t & 63;
    int wid = t >> 6;
    int base = t * S;
    bool live = (base < N_NODES);

    int v[S];
    int tot = 0;
#pragma unroll
    for (int i = 0; i < S / 4; ++i) {
        int4 q = make_int4(0, 0, 0, 0);
        if (live) q = *(const int4*)(deg + base + i * 4);
        v[i * 4 + 0] = q.x; v[i * 4 + 1] = q.y;
        v[i * 4 + 2] = q.z; v[i * 4 + 3] = q.w;
        tot += q.x + q.y + q.z + q.w;
    }
    int inc = tot;
#pragma unroll
    for (int off = 1; off < 64; off <<= 1) {
        int n = __shfl_up(inc, off);
        if (lane >= off) inc += n;
    }
    if (lane == 63) wsum[wid] = inc;
    __syncthreads();
    if (t < 16) {
        int wv = wsum[t];
        int winc = wv;
#pragma unroll
        for (int off = 1; off < 16; off <<= 1) {
            int n = __shfl_up(winc, off);
            if (t >= off) winc += n;
        }
        wsum[t] = winc - wv;
    }
    __syncthreads();
    int acc = wsum[wid] + (inc - tot);
#pragma unroll
    for (int i = 0; i < S / 4; ++i) {
        int4 r; float4 f;
        r.x = acc; f.x = rsqrtf((float)(v[i * 4 + 0] + 1)); acc += v[i * 4 + 0];
        r.y = acc; f.y = rsqrtf((float)(v[i * 4 + 1] + 1)); acc += v[i * 4 + 1];
        r.z = acc; f.z = rsqrtf((float)(v[i * 4 + 2] + 1)); acc += v[i * 4 + 2];
        r.w = acc; f.w = rsqrtf((float)(v[i * 4 + 3] + 1)); acc += v[i * 4 + 3];
        if (live) {
            *(int4*)(rowptr + base + i * 4) = r;
            *(float4*)(dinv + base + i * 4) = f;
        }
    }
    if (t == 0) rowptr[N_NODES] = N_EDGES;
}

__global__ void k_fill(const int* __restrict__ eidx, const int* __restrict__ rowptr,
                       int* __restrict__ cursor, int* __restrict__ col) {
    int e = blockIdx.x * blockDim.x + threadIdx.x;
    if (e < N_EDGES) {
        int s = eidx[e];
        int d = eidx[N_EDGES + e];
        int pos = atomicAdd(&cursor[d], 1);
        col[rowptr[d] + pos] = s;
    }
}

// ---------------- weight packing (B-fragment order) ----------------
// lane l holds B[k = kt*32 + (l>>4)*8 + j][col = nf*16 + (l&15)]
// packed at ((kt*NFB + nf)*64 + l)*8 + j

__global__ void k_pack_w1(const float* __restrict__ W, f16* __restrict__ Wp) {
    int u = blockIdx.x * blockDim.x + threadIdx.x;
    if (u >= 16 * 16 * 64) return;
    int l = u & 63;
    int nf = (u >> 6) & 15;
    int kt = u >> 10;
    int k0 = kt * 32 + (l >> 4) * 8;
    int c = nf * 16 + (l & 15);
    f16x8 o;
#pragma unroll
    for (int j = 0; j < 8; ++j) o[j] = (f16)W[(size_t)(k0 + j) * D_HID + c];
    *(f16x8*)(Wp + (size_t)u * 8) = o;
}

__global__ void k_pack_w2(const float* __restrict__ W, f16* __restrict__ Wp) {
    int u = blockIdx.x * blockDim.x + threadIdx.x;
    if (u >= 8 * 3 * 64) return;
    int l = u & 63;
    int nf = (u / 64) % 3;
    int kt = u / 192;
    int k0 = kt * 32 + (l >> 4) * 8;
    int c = nf * 16 + (l & 15);
    f16x8 o;
#pragma unroll
    for (int j = 0; j < 8; ++j)
        o[j] = (c < D_OUT) ? (f16)W[(size_t)(k0 + j) * D_OUT + c] : (f16)0.0f;
    *(f16x8*)(Wp + (size_t)u * 8) = o;
}

// ---------------- GEMM1: h1 = f16(x) @ W1, LDS-staged -------------------

__global__ __launch_bounds__(512) void k_gemm1(const float* __restrict__ X,
                                               const f16* __restrict__ Bp,
                                               f16* __restrict__ C) {
    __shared__ f16 As[64][520];
    int t = threadIdx.x;
    int lane = t & 63;
    int wid = t >> 6;
    int rowBase = blockIdx.x * 64;

#pragma unroll
    for (int it = 0; it < 16; ++it) {
        int idx = it * 512 + t;
        int row = idx >> 7;
        int c4 = idx & 127;
        float4 v = *(const float4*)(X + (size_t)(rowBase + row) * D_IN + c4 * 4);
        f16x4 o;
        o[0] = (f16)v.x; o[1] = (f16)v.y; o[2] = (f16)v.z; o[3] = (f16)v.w;
        *(f16x4*)(&As[row][c4 * 4]) = o;
    }
    __syncthreads();

    int nf0 = wid * 2;
    int r_ = lane & 15, q_ = lane >> 4;

    f32x4 acc[4][2];
#pragma unroll
    for (int mi = 0; mi < 4; ++mi)
#pragma unroll
        for (int ni = 0; ni < 2; ++ni) acc[mi][ni] = (f32x4)(0.0f);

#pragma unroll 4
    for (int kt = 0; kt < 16; ++kt) {
        f16x8 a[4], b[2];
#pragma unroll
        for (int mi = 0; mi < 4; ++mi)
            a[mi] = *(const f16x8*)(&As[mi * 16 + r_][kt * 32 + q_ * 8]);
#pragma unroll
        for (int ni = 0; ni < 2; ++ni)
            b[ni] = *(const f16x8*)(Bp + ((size_t)(kt * 16 + nf0 + ni) * 64 + lane) * 8);
#pragma unroll
        for (int mi = 0; mi < 4; ++mi)
#pragma unroll
            for (int ni = 0; ni < 2; ++ni)
                acc[mi][ni] = __builtin_amdgcn_mfma_f32_16x16x32_f16(a[mi], b[ni], acc[mi][ni], 0, 0, 0);
    }

    int r0 = q_ * 4;
    int c0 = r_;
#pragma unroll
    for (int mi = 0; mi < 4; ++mi)
#pragma unroll
        for (int ni = 0; ni < 2; ++ni)
#pragma unroll
            for (int r = 0; r < 4; ++r) {
                int row = rowBase + mi * 16 + r0 + r;
                C[(size_t)row * D_HID + (nf0 + ni) * 16 + c0] = (f16)acc[mi][ni][r];
            }
}

// ---------------- GEMM2 (packed A, LDS-free) ----------------

__global__ __launch_bounds__(256) void k_gemm2(const f16* __restrict__ Ap,
                                               const f16* __restrict__ Bp,
                                               f16* __restrict__ C) {
    int wid = threadIdx.x >> 6;
    int lane = threadIdx.x & 63;
    int rowTile = blockIdx.x * 4 + wid;
    int rowBase = rowTile * 64;
    if (rowBase >= N_NODES) return;

    f32x4 acc[4][3];
#pragma unroll
    for (int mi = 0; mi < 4; ++mi)
#pragma unroll
        for (int ni = 0; ni < 3; ++ni) acc[mi][ni] = (f32x4)(0.0f);

    int m16b = rowTile * 4;
    for (int kt = 0; kt < 8; ++kt) {
        f16x8 a[4], b[3];
#pragma unroll
        for (int mi = 0; mi < 4; ++mi)
            a[mi] = *(const f16x8*)(Ap + ((size_t)((m16b + mi) * 8 + kt) * 64 + lane) * 8);
#pragma unroll
        for (int ni = 0; ni < 3; ++ni)
            b[ni] = *(const f16x8*)(Bp + ((size_t)(kt * 3 + ni) * 64 + lane) * 8);
#pragma unroll
        for (int mi = 0; mi < 4; ++mi)
#pragma unroll
            for (int ni = 0; ni < 3; ++ni)
                acc[mi][ni] = __builtin_amdgcn_mfma_f32_16x16x32_f16(a[mi], b[ni], acc[mi][ni], 0, 0, 0);
    }

    int r0 = (lane >> 4) * 4;
    int c0 = lane & 15;
#pragma unroll
    for (int mi = 0; mi < 4; ++mi)
#pragma unroll
        for (int ni = 0; ni < 3; ++ni)
#pragma unroll
            for (int r = 0; r < 4; ++r) {
                int row = rowBase + mi * 16 + r0 + r;
                C[(size_t)row * D_OUT_PAD + ni * 16 + c0] = (f16)acc[mi][ni][r];
            }
}

// ---------------- aggregation 1: hp = packA(relu(Ahat*h1 + b1)) -----------
// Wave per node; half-wave (32 lanes x 16B) covers the 256-dim row.
// Halves take alternating edges, unroll 4 -> 8 independent gathers in
// flight per wave (was 4).

__global__ __launch_bounds__(256) void k_agg1(const f16* __restrict__ h1,
                                              const int* __restrict__ rowptr,
                                              const int* __restrict__ col,
                                              const float* __restrict__ dinv,
                                              const float* __restrict__ b1,
                                              f16* __restrict__ hp) {
    int node = blockIdx.x * 4 + (threadIdx.x >> 6);
    int lane = threadIdx.x & 63;
    int half = lane >> 5;
    int hl = lane & 31;
    float di = dinv[node];

    f16x8 selfv = *(const f16x8*)(h1 + (size_t)node * D_HID + hl * 8);

    float a[8];
#pragma unroll
    for (int j = 0; j < 8; ++j) a[j] = 0.0f;

    int e0 = rowptr[node], e1 = rowptr[node + 1];
    for (int base = e0; base < e1; base += 64) {
        int nn = min(64, e1 - base);
        int sidx = 0; float wv = 0.0f;
        if (lane < nn) {
            int s = col[base + lane];
            sidx = s;
            wv = dinv[s] * di;
        }
        int t = half;
        for (; t + 6 < nn; t += 8) {
            int s0 = __shfl(sidx, t),     s1 = __shfl(sidx, t + 2);
            int s2 = __shfl(sidx, t + 4), s3 = __shfl(sidx, t + 6);
            float w0 = __shfl(wv, t),     w1 = __shfl(wv, t + 2);
            float w2 = __shfl(wv, t + 4), w3 = __shfl(wv, t + 6);
            f16x8 u0 = *(const f16x8*)(h1 + (size_t)s0 * D_HID + hl * 8);
            f16x8 u1 = *(const f16x8*)(h1 + (size_t)s1 * D_HID + hl * 8);
            f16x8 u2 = *(const f16x8*)(h1 + (size_t)s2 * D_HID + hl * 8);
            f16x8 u3 = *(const f16x8*)(h1 + (size_t)s3 * D_HID + hl * 8);
#pragma unroll
            for (int j = 0; j < 8; ++j)
                a[j] += (float)u0[j] * w0 + (float)u1[j] * w1 +
                        (float)u2[j] * w2 + (float)u3[j] * w3;
        }
        for (; t + 2 < nn; t += 4) {
            int s0 = __shfl(sidx, t), s1 = __shfl(sidx, t + 2);
            float w0 = __shfl(wv, t), w1 = __shfl(wv, t + 2);
            f16x8 u0 = *(const f16x8*)(h1 + (size_t)s0 * D_HID + hl * 8);
            f16x8 u1 = *(const f16x8*)(h1 + (size_t)s1 * D_HID + hl * 8);
#pragma unroll
            for (int j = 0; j < 8; ++j)
                a[j] += (float)u0[j] * w0 + (float)u1[j] * w1;
        }
        if (t < nn) {
            int s0 = __shfl(sidx, t);
            float w0 = __shfl(wv, t);
            f16x8 u0 = *(const f16x8*)(h1 + (size_t)s0 * D_HID + hl * 8);
#pragma unroll
            for (int j = 0; j < 8; ++j) a[j] += (float)u0[j] * w0;
        }
    }

#pragma unroll
    for (int j = 0; j < 8; ++j) a[j] += __shfl_xor(a[j], 32);

    float wself = di * di;
    float4 b_lo = *(const float4*)(b1 + hl * 8);
    float4 b_hi = *(const float4*)(b1 + hl * 8 + 4);
    f16x8 o;
    o[0] = (f16)fmaxf(a[0] + (float)selfv[0] * wself + b_lo.x, 0.0f);
    o[1] = (f16)fmaxf(a[1] + (float)selfv[1] * wself + b_lo.y, 0.0f);
    o[2] = (f16)fmaxf(a[2] + (float)selfv[2] * wself + b_lo.z, 0.0f);
    o[3] = (f16)fmaxf(a[3] + (float)selfv[3] * wself + b_lo.w, 0.0f);
    o[4] = (f16)fmaxf(a[4] + (float)selfv[4] * wself + b_hi.x, 0.0f);
    o[5] = (f16)fmaxf(a[5] + (float)selfv[5] * wself + b_hi.y, 0.0f);
    o[6] = (f16)fmaxf(a[6] + (float)selfv[6] * wself + b_hi.z, 0.0f);
    o[7] = (f16)fmaxf(a[7] + (float)selfv[7] * wself + b_hi.w, 0.0f);

    if (half == 0) {
        size_t idx = ((size_t)(node >> 4) * 8 + (hl >> 2)) * 512 + (hl & 3) * 128 + (node & 15) * 8;
        *(f16x8*)(hp + idx) = o;
    }
}

// ---------------- aggregation 2: out = log_softmax(Ahat*g + b2) -----------
// g is 3.84 MB -> L2-resident; unroll 8 for request-rate.

__global__ __launch_bounds__(256) void k_agg2(const f16* __restrict__ g,
                                              const int* __restrict__ rowptr,
                                              const int* __restrict__ col,
                                              const float* __restrict__ dinv,
                                              const float* __restrict__ b2,
                                              float* __restrict__ out) {
    int node = blockIdx.x * 4 + (threadIdx.x >> 6);
    int lane = threadIdx.x & 63;
    float di = dinv[node];
    bool act = lane < D_OUT_PAD;
    float acc = act ? (float)g[(size_t)node * D_OUT_PAD + lane] * di * di : 0.0f;

    int e0 = rowptr[node], e1 = rowptr[node + 1];
    for (int base = e0; base < e1; base += 64) {
        int nn = min(64, e1 - base);
        int sidx = 0; float wv = 0.0f;
        if (lane < nn) {
            int s = col[base + lane];
            sidx = s;
            wv = dinv[s] * di;
        }
        int k = 0;
        for (; k + 8 <= nn; k += 8) {
            int s0 = __shfl(sidx, k),     s1 = __shfl(sidx, k + 1);
            int s2 = __shfl(sidx, k + 2), s3 = __shfl(sidx, k + 3);
            int s4 = __shfl(sidx, k + 4), s5 = __shfl(sidx, k + 5);
            int s6 = __shfl(sidx, k + 6), s7 = __shfl(sidx, k + 7);
            float w0 = __shfl(wv, k),     w1 = __shfl(wv, k + 1);
            float w2 = __shfl(wv, k + 2), w3 = __shfl(wv, k + 3);
            float w4 = __shfl(wv, k + 4), w5 = __shfl(wv, k + 5);
            float w6 = __shfl(wv, k + 6), w7 = __shfl(wv, k + 7);
            if (act) {
                float u0 = (float)g[(size_t)s0 * D_OUT_PAD + lane];
                float u1 = (float)g[(size_t)s1 * D_OUT_PAD + lane];
                float u2 = (float)g[(size_t)s2 * D_OUT_PAD + lane];
                float u3 = (float)g[(size_t)s3 * D_OUT_PAD + lane];
                float u4 = (float)g[(size_t)s4 * D_OUT_PAD + lane];
                float u5 = (float)g[(size_t)s5 * D_OUT_PAD + lane];
                float u6 = (float)g[(size_t)s6 * D_OUT_PAD + lane];
                float u7 = (float)g[(size_t)s7 * D_OUT_PAD + lane];
                acc += u0 * w0 + u1 * w1 + u2 * w2 + u3 * w3 +
                       u4 * w4 + u5 * w5 + u6 * w6 + u7 * w7;
            }
        }
        for (; k < nn; ++k) {
            int s0 = __shfl(sidx, k);
            float w0 = __shfl(wv, k);
            if (act) acc += (float)g[(size_t)s0 * D_OUT_PAD + lane] * w0;
        }
    }

    float z = (lane < D_OUT) ? acc + b2[lane] : -3.0e38f;
    float mx = z;
#pragma unroll
    for (int off = 32; off >= 1; off >>= 1) mx = fmaxf(mx, __shfl_xor(mx, off));
    float ex = (lane < D_OUT) ? expf(z - mx) : 0.0f;
    float sum = ex;
#pragma unroll
    for (int off = 32; off >= 1; off >>= 1) sum += __shfl_xor(sum, off);
    if (lane < D_OUT) out[(size_t)node * D_OUT + lane] = z - mx - logf(sum);
}

// ---------------- launcher ----------------

extern "C" void kernel_launch(void* const* d_in, const int* in_sizes, int n_in,
                              void* d_out, int out_size, void* d_ws, size_t ws_size,
                              hipStream_t stream) {
    const float* x  = (const float*)d_in[0];
    const int*   ei = (const int*)d_in[1];
    const float* W1 = (const float*)d_in[2];
    const float* b1 = (const float*)d_in[3];
    const float* W2 = (const float*)d_in[4];
    const float* b2 = (const float*)d_in[5];
    float* out = (float*)d_out;

    char* ws = (char*)d_ws;
    int*   degi   = (int*)(ws + 0);              // 160,000
    int*   cursor = (int*)(ws + 160000);         // 160,000
    float* dinv   = (float*)(ws + 320000);       // 160,000
    int*   rowptr = (int*)(ws + 480000);         // 160,256 (40001 ints)
    int*   col    = (int*)(ws + 640256);         // 2,560,000
    f16*   w1p    = (f16*)(ws + 3200256);        // 262,144
    f16*   w2p    = (f16*)(ws + 3462400);        // 24,576
    f16*   h1     = (f16*)(ws + 3486976);        // 20,480,000
    f16*   hpk    = (f16*)(ws + 23966976);       // 20,480,000 (packed A, GEMM2)
    f16*   g      = (f16*)(ws + 44446976);       // 3,840,000
    // total 48,286,976 bytes

    hipMemsetAsync(d_ws, 0, 320000, stream);  // degi + cursor

    k_degree<<<2500, 256, 0, stream>>>(ei, degi);
    k_scan<<<1, 1024, 0, stream>>>(degi, rowptr, dinv);
    k_fill<<<2500, 256, 0, stream>>>(ei, rowptr, cursor, col);

    k_pack_w1<<<64, 256, 0, stream>>>(W1, w1p);
    k_pack_w2<<<6, 256, 0, stream>>>(W2, w2p);

    k_gemm1<<<625, 512, 0, stream>>>(x, w1p, h1);
    k_agg1<<<10000, 256, 0, stream>>>(h1, rowptr, col, dinv, b1, hpk);
    k_gemm2<<<157, 256, 0, stream>>>(hpk, w2p, g);
    k_agg2<<<10000, 256, 0, stream>>>(g, rowptr, col, dinv, b2, out);
}

// Round 8
// 193.948 us; speedup vs baseline: 1.0279x; 1.0279x over previous
//
#include <hip/hip_runtime.h>

// ---------------------------------------------------------------------------
// GCN 2-layer forward on MI355X.  7 dispatches:
//   k_init:   zero deg/cursor + pack W1,W2 -> MFMA B-fragments (one kernel)
//   k_degree: deg[dst]++                         (int atomics)
//   k_scan:   rowptr = exscan(deg) + dinv=rsqrt(deg+1)   (parallel, 1 block)
//   k_fill:   col[rowptr[dst]+pos++] = src       (CSR by dst)
//   k_gemm1:  h1 = f16(x) @ W1   (LDS-staged, coalesced, ds_read_b128 frags)
//   k_agg1g2: per 64-node block: hrelu=relu(Ahat*h1+b1) -> LDS tile,
//             then MFMA  g = hrelu @ W2  (fused; no hpk round-trip)
//   k_agg2:   out = log_softmax(Ahat*g + b2)
// agg1 gather is at its L2-miss roofline (143MB compulsory-ish, ~3.5TB/s EA).
// ---------------------------------------------------------------------------

typedef _Float16 f16;
typedef _Float16 f16x8 __attribute__((ext_vector_type(8)));
typedef _Float16 f16x4 __attribute__((ext_vector_type(4)));
typedef float f32x4 __attribute__((ext_vector_type(4)));

#define N_NODES 40000
#define N_EDGES 640000
#define D_IN 512
#define D_HID 256
#define D_OUT 47
#define D_OUT_PAD 48
#define HS_LD 262   // 256 + 6 pad: LDS row stride (131 dwords, odd-ish -> <=4-way)

// ---------------- init: zero counters + pack weights ----------------
// B-fragment order: lane l holds B[k=kt*32+(l>>4)*8+j][col=nf*16+(l&15)]
// packed at ((kt*NFB+nf)*64+l)*8+j.   W1: KT=16,NFB=16. W2: KT=8,NFB=3 (pad 48).

__global__ void k_init(const float* __restrict__ W1, const float* __restrict__ W2,
                       f16* __restrict__ w1p, f16* __restrict__ w2p,
                       int* __restrict__ zeroes) {
    int bid = blockIdx.x;
    int t = threadIdx.x;
    if (bid < 64) {                       // pack W1: 16384 units
        int u = bid * 256 + t;
        int l = u & 63;
        int nf = (u >> 6) & 15;
        int kt = u >> 10;
        int k0 = kt * 32 + (l >> 4) * 8;
        int c = nf * 16 + (l & 15);
        f16x8 o;
#pragma unroll
        for (int j = 0; j < 8; ++j) o[j] = (f16)W1[(size_t)(k0 + j) * D_HID + c];
        *(f16x8*)(w1p + (size_t)u * 8) = o;
    } else if (bid < 70) {                // pack W2: 1536 units
        int u = (bid - 64) * 256 + t;
        int l = u & 63;
        int nf = (u / 64) % 3;
        int kt = u / 192;
        int k0 = kt * 32 + (l >> 4) * 8;
        int c = nf * 16 + (l & 15);
        f16x8 o;
#pragma unroll
        for (int j = 0; j < 8; ++j)
            o[j] = (c < D_OUT) ? (f16)W2[(size_t)(k0 + j) * D_OUT + c] : (f16)0.0f;
        *(f16x8*)(w2p + (size_t)u * 8) = o;
    } else {                              // zero deg+cursor: 80000 ints
        int i = (bid - 70) * 256 + t;
        if (i < 80000) zeroes[i] = 0;
    }
}

// ---------------- CSR build ----------------

__global__ void k_degree(const int* __restrict__ eidx, int* __restrict__ deg) {
    int e = blockIdx.x * blockDim.x + threadIdx.x;
    if (e < N_EDGES) atomicAdd(&deg[eidx[N_EDGES + e]], 1);
}

__global__ __launch_bounds__(1024) void k_scan(const int* __restrict__ deg,
                                               int* __restrict__ rowptr,
                                               float* __restrict__ dinv) {
    __shared__ int wsum[16];
    const int S = 40;
    int t = threadIdx.x;
    int lane = t & 63;
    int wid = t >> 6;
    int base = t * S;
    bool live = (base < N_NODES);

    int v[S];
    int tot = 0;
#pragma unroll
    for (int i = 0; i < S / 4; ++i) {
        int4 q = make_int4(0, 0, 0, 0);
        if (live) q = *(const int4*)(deg + base + i * 4);
        v[i * 4 + 0] = q.x; v[i * 4 + 1] = q.y;
        v[i * 4 + 2] = q.z; v[i * 4 + 3] = q.w;
        tot += q.x + q.y + q.z + q.w;
    }
    int inc = tot;
#pragma unroll
    for (int off = 1; off < 64; off <<= 1) {
        int n = __shfl_up(inc, off);
        if (lane >= off) inc += n;
    }
    if (lane == 63) wsum[wid] = inc;
    __syncthreads();
    if (t < 16) {
        int wv = wsum[t];
        int winc = wv;
#pragma unroll
        for (int off = 1; off < 16; off <<= 1) {
            int n = __shfl_up(winc, off);
            if (t >= off) winc += n;
        }
        wsum[t] = winc - wv;
    }
    __syncthreads();
    int acc = wsum[wid] + (inc - tot);
#pragma unroll
    for (int i = 0; i < S / 4; ++i) {
        int4 r; float4 f;
        r.x = acc; f.x = rsqrtf((float)(v[i * 4 + 0] + 1)); acc += v[i * 4 + 0];
        r.y = acc; f.y = rsqrtf((float)(v[i * 4 + 1] + 1)); acc += v[i * 4 + 1];
        r.z = acc; f.z = rsqrtf((float)(v[i * 4 + 2] + 1)); acc += v[i * 4 + 2];
        r.w = acc; f.w = rsqrtf((float)(v[i * 4 + 3] + 1)); acc += v[i * 4 + 3];
        if (live) {
            *(int4*)(rowptr + base + i * 4) = r;
            *(float4*)(dinv + base + i * 4) = f;
        }
    }
    if (t == 0) rowptr[N_NODES] = N_EDGES;
}

__global__ void k_fill(const int* __restrict__ eidx, const int* __restrict__ rowptr,
                       int* __restrict__ cursor, int* __restrict__ col) {
    int e = blockIdx.x * blockDim.x + threadIdx.x;
    if (e < N_EDGES) {
        int s = eidx[e];
        int d = eidx[N_EDGES + e];
        int pos = atomicAdd(&cursor[d], 1);
        col[rowptr[d] + pos] = s;
    }
}

// ---------------- GEMM1: h1 = f16(x) @ W1, LDS-staged -------------------

__global__ __launch_bounds__(512) void k_gemm1(const float* __restrict__ X,
                                               const f16* __restrict__ Bp,
                                               f16* __restrict__ C) {
    __shared__ f16 As[64][520];
    int t = threadIdx.x;
    int lane = t & 63;
    int wid = t >> 6;
    int rowBase = blockIdx.x * 64;

#pragma unroll
    for (int it = 0; it < 16; ++it) {
        int idx = it * 512 + t;
        int row = idx >> 7;
        int c4 = idx & 127;
        float4 v = *(const float4*)(X + (size_t)(rowBase + row) * D_IN + c4 * 4);
        f16x4 o;
        o[0] = (f16)v.x; o[1] = (f16)v.y; o[2] = (f16)v.z; o[3] = (f16)v.w;
        *(f16x4*)(&As[row][c4 * 4]) = o;
    }
    __syncthreads();

    int nf0 = wid * 2;
    int r_ = lane & 15, q_ = lane >> 4;

    f32x4 acc[4][2];
#pragma unroll
    for (int mi = 0; mi < 4; ++mi)
#pragma unroll
        for (int ni = 0; ni < 2; ++ni) acc[mi][ni] = (f32x4)(0.0f);

#pragma unroll 4
    for (int kt = 0; kt < 16; ++kt) {
        f16x8 a[4], b[2];
#pragma unroll
        for (int mi = 0; mi < 4; ++mi)
            a[mi] = *(const f16x8*)(&As[mi * 16 + r_][kt * 32 + q_ * 8]);
#pragma unroll
        for (int ni = 0; ni < 2; ++ni)
            b[ni] = *(const f16x8*)(Bp + ((size_t)(kt * 16 + nf0 + ni) * 64 + lane) * 8);
#pragma unroll
        for (int mi = 0; mi < 4; ++mi)
#pragma unroll
            for (int ni = 0; ni < 2; ++ni)
                acc[mi][ni] = __builtin_amdgcn_mfma_f32_16x16x32_f16(a[mi], b[ni], acc[mi][ni], 0, 0, 0);
    }

    int r0 = q_ * 4;
    int c0 = r_;
#pragma unroll
    for (int mi = 0; mi < 4; ++mi)
#pragma unroll
        for (int ni = 0; ni < 2; ++ni)
#pragma unroll
            for (int r = 0; r < 4; ++r) {
                int row = rowBase + mi * 16 + r0 + r;
                C[(size_t)row * D_HID + (nf0 + ni) * 16 + c0] = (f16)acc[mi][ni][r];
            }
}

// -------- fused agg1 + gemm2: g = (relu(Ahat*h1+b1)) @ W2 ----------------
// 625 blocks x 4 waves. Block owns 64 nodes; wave w gathers nodes w*16..+16
// into LDS hs[64][HS_LD] (row-major hrelu tile). One barrier, then waves 0-2
// MFMA the 64x256 @ 256x48 tile and write g rows directly.

__global__ __launch_bounds__(256) void k_agg1g2(const f16* __restrict__ h1,
                                                const int* __restrict__ rowptr,
                                                const int* __restrict__ col,
                                                const float* __restrict__ dinv,
                                                const float* __restrict__ b1,
                                                const f16* __restrict__ w2p,
                                                f16* __restrict__ g) {
    __shared__ f16 hs[64][HS_LD];
    int t = threadIdx.x;
    int lane = t & 63;
    int wid = t >> 6;
    int half = lane >> 5;
    int hl = lane & 31;
    int nodeBase = blockIdx.x * 64 + wid * 16;

    float4 b_lo = *(const float4*)(b1 + hl * 8);
    float4 b_hi = *(const float4*)(b1 + hl * 8 + 4);

    for (int i = 0; i < 16; ++i) {
        int node = nodeBase + i;
        float di = dinv[node];
        f16x8 selfv = *(const f16x8*)(h1 + (size_t)node * D_HID + hl * 8);

        float a[8];
#pragma unroll
        for (int j = 0; j < 8; ++j) a[j] = 0.0f;

        int e0 = rowptr[node], e1 = rowptr[node + 1];
        for (int base = e0; base < e1; base += 64) {
            int nn = min(64, e1 - base);
            int sidx = 0; float wv = 0.0f;
            if (lane < nn) {
                int s = col[base + lane];
                sidx = s;
                wv = dinv[s] * di;
            }
            int e = half;
            for (; e + 6 < nn; e += 8) {
                int s0 = __shfl(sidx, e),     s1 = __shfl(sidx, e + 2);
                int s2 = __shfl(sidx, e + 4), s3 = __shfl(sidx, e + 6);
                float w0 = __shfl(wv, e),     w1 = __shfl(wv, e + 2);
                float w2 = __shfl(wv, e + 4), w3 = __shfl(wv, e + 6);
                f16x8 u0 = *(const f16x8*)(h1 + (size_t)s0 * D_HID + hl * 8);
                f16x8 u1 = *(const f16x8*)(h1 + (size_t)s1 * D_HID + hl * 8);
                f16x8 u2 = *(const f16x8*)(h1 + (size_t)s2 * D_HID + hl * 8);
                f16x8 u3 = *(const f16x8*)(h1 + (size_t)s3 * D_HID + hl * 8);
#pragma unroll
                for (int j = 0; j < 8; ++j)
                    a[j] += (float)u0[j] * w0 + (float)u1[j] * w1 +
                            (float)u2[j] * w2 + (float)u3[j] * w3;
            }
            for (; e + 2 < nn; e += 4) {
                int s0 = __shfl(sidx, e), s1 = __shfl(sidx, e + 2);
                float w0 = __shfl(wv, e), w1 = __shfl(wv, e + 2);
                f16x8 u0 = *(const f16x8*)(h1 + (size_t)s0 * D_HID + hl * 8);
                f16x8 u1 = *(const f16x8*)(h1 + (size_t)s1 * D_HID + hl * 8);
#pragma unroll
                for (int j = 0; j < 8; ++j)
                    a[j] += (float)u0[j] * w0 + (float)u1[j] * w1;
            }
            if (e < nn) {
                int s0 = __shfl(sidx, e);
                float w0 = __shfl(wv, e);
                f16x8 u0 = *(const f16x8*)(h1 + (size_t)s0 * D_HID + hl * 8);
#pragma unroll
                for (int j = 0; j < 8; ++j) a[j] += (float)u0[j] * w0;
            }
        }

#pragma unroll
        for (int j = 0; j < 8; ++j) a[j] += __shfl_xor(a[j], 32);

        float wself = di * di;
        f16x8 o;
        o[0] = (f16)fmaxf(a[0] + (float)selfv[0] * wself + b_lo.x, 0.0f);
        o[1] = (f16)fmaxf(a[1] + (float)selfv[1] * wself + b_lo.y, 0.0f);
        o[2] = (f16)fmaxf(a[2] + (float)selfv[2] * wself + b_lo.z, 0.0f);
        o[3] = (f16)fmaxf(a[3] + (float)selfv[3] * wself + b_lo.w, 0.0f);
        o[4] = (f16)fmaxf(a[4] + (float)selfv[4] * wself + b_hi.x, 0.0f);
        o[5] = (f16)fmaxf(a[5] + (float)selfv[5] * wself + b_hi.y, 0.0f);
        o[6] = (f16)fmaxf(a[6] + (float)selfv[6] * wself + b_hi.z, 0.0f);
        o[7] = (f16)fmaxf(a[7] + (float)selfv[7] * wself + b_hi.w, 0.0f);

        if (half == 0) *(f16x8*)(&hs[wid * 16 + i][hl * 8]) = o;
    }
    __syncthreads();

    if (wid < 3) {  // MFMA: 64 rows x 16 cols per wave (3 col-frags total)
        int nf = wid;
        int r_ = lane & 15, q_ = lane >> 4;
        f32x4 acc[4];
#pragma unroll
        for (int mi = 0; mi < 4; ++mi) acc[mi] = (f32x4)(0.0f);

#pragma unroll
        for (int kt = 0; kt < 8; ++kt) {
            f16x8 b = *(const f16x8*)(w2p + ((size_t)(kt * 3 + nf) * 64 + lane) * 8);
#pragma unroll
            for (int mi = 0; mi < 4; ++mi) {
                f16x8 a = *(const f16x8*)(&hs[mi * 16 + r_][kt * 32 + q_ * 8]);
                acc[mi] = __builtin_amdgcn_mfma_f32_16x16x32_f16(a, b, acc[mi], 0, 0, 0);
            }
        }

        int rowBase = blockIdx.x * 64;
#pragma unroll
        for (int mi = 0; mi < 4; ++mi)
#pragma unroll
            for (int r = 0; r < 4; ++r) {
                int row = rowBase + mi * 16 + q_ * 4 + r;
                g[(size_t)row * D_OUT_PAD + nf * 16 + r_] = (f16)acc[mi][r];
            }
    }
}

// ---------------- aggregation 2: out = log_softmax(Ahat*g + b2) -----------

__global__ __launch_bounds__(256) void k_agg2(const f16* __restrict__ g,
                                              const int* __restrict__ rowptr,
                                              const int* __restrict__ col,
                                              const float* __restrict__ dinv,
                                              const float* __restrict__ b2,
                                              float* __restrict__ out) {
    int node = blockIdx.x * 4 + (threadIdx.x >> 6);
    int lane = threadIdx.x & 63;
    float di = dinv[node];
    bool act = lane < D_OUT_PAD;
    float acc = act ? (float)g[(size_t)node * D_OUT_PAD + lane] * di * di : 0.0f;

    int e0 = rowptr[node], e1 = rowptr[node + 1];
    for (int base = e0; base < e1; base += 64) {
        int nn = min(64, e1 - base);
        int sidx = 0; float wv = 0.0f;
        if (lane < nn) {
            int s = col[base + lane];
            sidx = s;
            wv = dinv[s] * di;
        }
        int k = 0;
        for (; k + 8 <= nn; k += 8) {
            int s0 = __shfl(sidx, k),     s1 = __shfl(sidx, k + 1);
            int s2 = __shfl(sidx, k + 2), s3 = __shfl(sidx, k + 3);
            int s4 = __shfl(sidx, k + 4), s5 = __shfl(sidx, k + 5);
            int s6 = __shfl(sidx, k + 6), s7 = __shfl(sidx, k + 7);
            float w0 = __shfl(wv, k),     w1 = __shfl(wv, k + 1);
            float w2 = __shfl(wv, k + 2), w3 = __shfl(wv, k + 3);
            float w4 = __shfl(wv, k + 4), w5 = __shfl(wv, k + 5);
            float w6 = __shfl(wv, k + 6), w7 = __shfl(wv, k + 7);
            if (act) {
                float u0 = (float)g[(size_t)s0 * D_OUT_PAD + lane];
                float u1 = (float)g[(size_t)s1 * D_OUT_PAD + lane];
                float u2 = (float)g[(size_t)s2 * D_OUT_PAD + lane];
                float u3 = (float)g[(size_t)s3 * D_OUT_PAD + lane];
                float u4 = (float)g[(size_t)s4 * D_OUT_PAD + lane];
                float u5 = (float)g[(size_t)s5 * D_OUT_PAD + lane];
                float u6 = (float)g[(size_t)s6 * D_OUT_PAD + lane];
                float u7 = (float)g[(size_t)s7 * D_OUT_PAD + lane];
                acc += u0 * w0 + u1 * w1 + u2 * w2 + u3 * w3 +
                       u4 * w4 + u5 * w5 + u6 * w6 + u7 * w7;
            }
        }
        for (; k < nn; ++k) {
            int s0 = __shfl(sidx, k);
            float w0 = __shfl(wv, k);
            if (act) acc += (float)g[(size_t)s0 * D_OUT_PAD + lane] * w0;
        }
    }

    float z = (lane < D_OUT) ? acc + b2[lane] : -3.0e38f;
    float mx = z;
#pragma unroll
    for (int off = 32; off >= 1; off >>= 1) mx = fmaxf(mx, __shfl_xor(mx, off));
    float ex = (lane < D_OUT) ? expf(z - mx) : 0.0f;
    float sum = ex;
#pragma unroll
    for (int off = 32; off >= 1; off >>= 1) sum += __shfl_xor(sum, off);
    if (lane < D_OUT) out[(size_t)node * D_OUT + lane] = z - mx - logf(sum);
}

// ---------------- launcher ----------------

extern "C" void kernel_launch(void* const* d_in, const int* in_sizes, int n_in,
                              void* d_out, int out_size, void* d_ws, size_t ws_size,
                              hipStream_t stream) {
    const float* x  = (const float*)d_in[0];
    const int*   ei = (const int*)d_in[1];
    const float* W1 = (const float*)d_in[2];
    const float* b1 = (const float*)d_in[3];
    const float* W2 = (const float*)d_in[4];
    const float* b2 = (const float*)d_in[5];
    float* out = (float*)d_out;

    char* ws = (char*)d_ws;
    int*   degi   = (int*)(ws + 0);              // 160,000 (deg)
    int*   cursor = (int*)(ws + 160000);         // 160,000
    float* dinv   = (float*)(ws + 320000);       // 160,000
    int*   rowptr = (int*)(ws + 480000);         // 160,256 (40001 ints)
    int*   col    = (int*)(ws + 640256);         // 2,560,000
    f16*   w1p    = (f16*)(ws + 3200256);        // 262,144
    f16*   w2p    = (f16*)(ws + 3462400);        // 24,576
    f16*   h1     = (f16*)(ws + 3486976);        // 20,480,000
    f16*   g      = (f16*)(ws + 23966976);       // 3,840,000
    // total < 28 MB

    k_init<<<383, 256, 0, stream>>>(W1, W2, w1p, w2p, degi);
    k_degree<<<2500, 256, 0, stream>>>(ei, degi);
    k_scan<<<1, 1024, 0, stream>>>(degi, rowptr, dinv);
    k_fill<<<2500, 256, 0, stream>>>(ei, rowptr, cursor, col);

    k_gemm1<<<625, 512, 0, stream>>>(x, w1p, h1);
    k_agg1g2<<<625, 256, 0, stream>>>(h1, rowptr, col, dinv, b1, w2p, g);
    k_agg2<<<10000, 256, 0, stream>>>(g, rowptr, col, dinv, b2, out);
}

// Round 10
// 193.001 us; speedup vs baseline: 1.0330x; 1.0049x over previous
//
#include <hip/hip_runtime.h>

// ---------------------------------------------------------------------------
// GCN 2-layer forward on MI355X.  8 dispatches.
// NOTE: agg1/agg2/gemm1/gemm2/fill sources are frozen at the R6 versions —
// their exact f32 summation structure reproduces absmax 0.0625 (3/3 passes).
// Do NOT restructure aggregation math; the bf16-floored reference comparison
// is sensitive to it (fused variants measured 0.078-0.094, threshold 0.085).
//   k_init:   zero deg/cursor + pack W1,W2 -> MFMA B-fragments
//   k_degree: deg[dst]++                         (int atomics)
//   k_scan:   rowptr = exscan(deg) + dinv=rsqrt(deg+1)   (parallel, 1 block)
//   k_fill:   col[rowptr[dst]+pos++] = src       (CSR by dst)
//   k_gemm1:  h1 = f16(x) @ W1   (LDS-staged, coalesced, ds_read_b128 frags)
//   k_agg1:   hp = packA(relu(Ahat*h1 + b1))  (8 gathers in flight per wave)
//   k_gemm2:  g = hp @ W2  (48 cols, col47 zero)
//   k_agg2:   out = log_softmax(Ahat*g + b2)  (unroll 8, L2-resident g)
// agg1 gather: ~143MB L2-miss compulsory at ~3.5TB/s => ~41-48us floor (f16).
// ---------------------------------------------------------------------------

typedef _Float16 f16;
typedef _Float16 f16x8 __attribute__((ext_vector_type(8)));
typedef _Float16 f16x4 __attribute__((ext_vector_type(4)));
typedef float f32x4 __attribute__((ext_vector_type(4)));

#define N_NODES 40000
#define N_EDGES 640000
#define D_IN 512
#define D_HID 256
#define D_OUT 47
#define D_OUT_PAD 48

// ---------------- init: zero counters + pack weights ----------------
// B-fragment order: lane l holds B[k=kt*32+(l>>4)*8+j][col=nf*16+(l&15)]
// packed at ((kt*NFB+nf)*64+l)*8+j.   W1: KT=16,NFB=16. W2: KT=8,NFB=3.

__global__ void k_init(const float* __restrict__ W1, const float* __restrict__ W2,
                       f16* __restrict__ w1p, f16* __restrict__ w2p,
                       int* __restrict__ zeroes) {
    int bid = blockIdx.x;
    int t = threadIdx.x;
    if (bid < 64) {                       // pack W1: 16384 units
        int u = bid * 256 + t;
        int l = u & 63;
        int nf = (u >> 6) & 15;
        int kt = u >> 10;
        int k0 = kt * 32 + (l >> 4) * 8;
        int c = nf * 16 + (l & 15);
        f16x8 o;
#pragma unroll
        for (int j = 0; j < 8; ++j) o[j] = (f16)W1[(size_t)(k0 + j) * D_HID + c];
        *(f16x8*)(w1p + (size_t)u * 8) = o;
    } else if (bid < 70) {                // pack W2: 1536 units
        int u = (bid - 64) * 256 + t;
        int l = u & 63;
        int nf = (u / 64) % 3;
        int kt = u / 192;
        int k0 = kt * 32 + (l >> 4) * 8;
        int c = nf * 16 + (l & 15);
        f16x8 o;
#pragma unroll
        for (int j = 0; j < 8; ++j)
            o[j] = (c < D_OUT) ? (f16)W2[(size_t)(k0 + j) * D_OUT + c] : (f16)0.0f;
        *(f16x8*)(w2p + (size_t)u * 8) = o;
    } else {                              // zero deg+cursor: 80000 ints
        int i = (bid - 70) * 256 + t;
        if (i < 80000) zeroes[i] = 0;
    }
}

// ---------------- CSR build ----------------

__global__ void k_degree(const int* __restrict__ eidx, int* __restrict__ deg) {
    int e = blockIdx.x * blockDim.x + threadIdx.x;
    if (e < N_EDGES) atomicAdd(&deg[eidx[N_EDGES + e]], 1);
}

__global__ __launch_bounds__(1024) void k_scan(const int* __restrict__ deg,
                                               int* __restrict__ rowptr,
                                               float* __restrict__ dinv) {
    __shared__ int wsum[16];
    const int S = 40;
    int t = threadIdx.x;
    int lane = t & 63;
    int wid = t >> 6;
    int base = t * S;
    bool live = (base < N_NODES);

    int v[S];
    int tot = 0;
#pragma unroll
    for (int i = 0; i < S / 4; ++i) {
        int4 q = make_int4(0, 0, 0, 0);
        if (live) q = *(const int4*)(deg + base + i * 4);
        v[i * 4 + 0] = q.x; v[i * 4 + 1] = q.y;
        v[i * 4 + 2] = q.z; v[i * 4 + 3] = q.w;
        tot += q.x + q.y + q.z + q.w;
    }
    int inc = tot;
#pragma unroll
    for (int off = 1; off < 64; off <<= 1) {
        int n = __shfl_up(inc, off);
        if (lane >= off) inc += n;
    }
    if (lane == 63) wsum[wid] = inc;
    __syncthreads();
    if (t < 16) {
        int wv = wsum[t];
        int winc = wv;
#pragma unroll
        for (int off = 1; off < 16; off <<= 1) {
            int n = __shfl_up(winc, off);
            if (t >= off) winc += n;
        }
        wsum[t] = winc - wv;
    }
    __syncthreads();
    int acc = wsum[wid] + (inc - tot);
#pragma unroll
    for (int i = 0; i < S / 4; ++i) {
        int4 r; float4 f;
        r.x = acc; f.x = rsqrtf((float)(v[i * 4 + 0] + 1)); acc += v[i * 4 + 0];
        r.y = acc; f.y = rsqrtf((float)(v[i * 4 + 1] + 1)); acc += v[i * 4 + 1];
        r.z = acc; f.z = rsqrtf((float)(v[i * 4 + 2] + 1)); acc += v[i * 4 + 2];
        r.w = acc; f.w = rsqrtf((float)(v[i * 4 + 3] + 1)); acc += v[i * 4 + 3];
        if (live) {
            *(int4*)(rowptr + base + i * 4) = r;
            *(float4*)(dinv + base + i * 4) = f;
        }
    }
    if (t == 0) rowptr[N_NODES] = N_EDGES;
}

__global__ void k_fill(const int* __restrict__ eidx, const int* __restrict__ rowptr,
                       int* __restrict__ cursor, int* __restrict__ col) {
    int e = blockIdx.x * blockDim.x + threadIdx.x;
    if (e < N_EDGES) {
        int s = eidx[e];
        int d = eidx[N_EDGES + e];
        int pos = atomicAdd(&cursor[d], 1);
        col[rowptr[d] + pos] = s;
    }
}

// ---------------- GEMM1: h1 = f16(x) @ W1, LDS-staged -------------------

__global__ __launch_bounds__(512) void k_gemm1(const float* __restrict__ X,
                                               const f16* __restrict__ Bp,
                                               f16* __restrict__ C) {
    __shared__ f16 As[64][520];
    int t = threadIdx.x;
    int lane = t & 63;
    int wid = t >> 6;
    int rowBase = blockIdx.x * 64;

#pragma unroll
    for (int it = 0; it < 16; ++it) {
        int idx = it * 512 + t;
        int row = idx >> 7;
        int c4 = idx & 127;
        float4 v = *(const float4*)(X + (size_t)(rowBase + row) * D_IN + c4 * 4);
        f16x4 o;
        o[0] = (f16)v.x; o[1] = (f16)v.y; o[2] = (f16)v.z; o[3] = (f16)v.w;
        *(f16x4*)(&As[row][c4 * 4]) = o;
    }
    __syncthreads();

    int nf0 = wid * 2;
    int r_ = lane & 15, q_ = lane >> 4;

    f32x4 acc[4][2];
#pragma unroll
    for (int mi = 0; mi < 4; ++mi)
#pragma unroll
        for (int ni = 0; ni < 2; ++ni) acc[mi][ni] = (f32x4)(0.0f);

#pragma unroll 4
    for (int kt = 0; kt < 16; ++kt) {
        f16x8 a[4], b[2];
#pragma unroll
        for (int mi = 0; mi < 4; ++mi)
            a[mi] = *(const f16x8*)(&As[mi * 16 + r_][kt * 32 + q_ * 8]);
#pragma unroll
        for (int ni = 0; ni < 2; ++ni)
            b[ni] = *(const f16x8*)(Bp + ((size_t)(kt * 16 + nf0 + ni) * 64 + lane) * 8);
#pragma unroll
        for (int mi = 0; mi < 4; ++mi)
#pragma unroll
            for (int ni = 0; ni < 2; ++ni)
                acc[mi][ni] = __builtin_amdgcn_mfma_f32_16x16x32_f16(a[mi], b[ni], acc[mi][ni], 0, 0, 0);
    }

    int r0 = q_ * 4;
    int c0 = r_;
#pragma unroll
    for (int mi = 0; mi < 4; ++mi)
#pragma unroll
        for (int ni = 0; ni < 2; ++ni)
#pragma unroll
            for (int r = 0; r < 4; ++r) {
                int row = rowBase + mi * 16 + r0 + r;
                C[(size_t)row * D_HID + (nf0 + ni) * 16 + c0] = (f16)acc[mi][ni][r];
            }
}

// ---------------- GEMM2 (packed A, LDS-free) ----------------

__global__ __launch_bounds__(256) void k_gemm2(const f16* __restrict__ Ap,
                                               const f16* __restrict__ Bp,
                                               f16* __restrict__ C) {
    int wid = threadIdx.x >> 6;
    int lane = threadIdx.x & 63;
    int rowTile = blockIdx.x * 4 + wid;
    int rowBase = rowTile * 64;
    if (rowBase >= N_NODES) return;

    f32x4 acc[4][3];
#pragma unroll
    for (int mi = 0; mi < 4; ++mi)
#pragma unroll
        for (int ni = 0; ni < 3; ++ni) acc[mi][ni] = (f32x4)(0.0f);

    int m16b = rowTile * 4;
    for (int kt = 0; kt < 8; ++kt) {
        f16x8 a[4], b[3];
#pragma unroll
        for (int mi = 0; mi < 4; ++mi)
            a[mi] = *(const f16x8*)(Ap + ((size_t)((m16b + mi) * 8 + kt) * 64 + lane) * 8);
#pragma unroll
        for (int ni = 0; ni < 3; ++ni)
            b[ni] = *(const f16x8*)(Bp + ((size_t)(kt * 3 + ni) * 64 + lane) * 8);
#pragma unroll
        for (int mi = 0; mi < 4; ++mi)
#pragma unroll
            for (int ni = 0; ni < 3; ++ni)
                acc[mi][ni] = __builtin_amdgcn_mfma_f32_16x16x32_f16(a[mi], b[ni], acc[mi][ni], 0, 0, 0);
    }

    int r0 = (lane >> 4) * 4;
    int c0 = lane & 15;
#pragma unroll
    for (int mi = 0; mi < 4; ++mi)
#pragma unroll
        for (int ni = 0; ni < 3; ++ni)
#pragma unroll
            for (int r = 0; r < 4; ++r) {
                int row = rowBase + mi * 16 + r0 + r;
                C[(size_t)row * D_OUT_PAD + ni * 16 + c0] = (f16)acc[mi][ni][r];
            }
}

// ---------------- aggregation 1: hp = packA(relu(Ahat*h1 + b1)) -----------
// Wave per node; half-wave (32 lanes x 16B) covers the 256-dim row.
// Halves take alternating edges, unroll 4 -> 8 independent gathers in flight.

__global__ __launch_bounds__(256) void k_agg1(const f16* __restrict__ h1,
                                              const int* __restrict__ rowptr,
                                              const int* __restrict__ col,
                                              const float* __restrict__ dinv,
                                              const float* __restrict__ b1,
                                              f16* __restrict__ hp) {
    int node = blockIdx.x * 4 + (threadIdx.x >> 6);
    int lane = threadIdx.x & 63;
    int half = lane >> 5;
    int hl = lane & 31;
    float di = dinv[node];

    f16x8 selfv = *(const f16x8*)(h1 + (size_t)node * D_HID + hl * 8);

    float a[8];
#pragma unroll
    for (int j = 0; j < 8; ++j) a[j] = 0.0f;

    int e0 = rowptr[node], e1 = rowptr[node + 1];
    for (int base = e0; base < e1; base += 64) {
        int nn = min(64, e1 - base);
        int sidx = 0; float wv = 0.0f;
        if (lane < nn) {
            int s = col[base + lane];
            sidx = s;
            wv = dinv[s] * di;
        }
        int t = half;
        for (; t + 6 < nn; t += 8) {
            int s0 = __shfl(sidx, t),     s1 = __shfl(sidx, t + 2);
            int s2 = __shfl(sidx, t + 4), s3 = __shfl(sidx, t + 6);
            float w0 = __shfl(wv, t),     w1 = __shfl(wv, t + 2);
            float w2 = __shfl(wv, t + 4), w3 = __shfl(wv, t + 6);
            f16x8 u0 = *(const f16x8*)(h1 + (size_t)s0 * D_HID + hl * 8);
            f16x8 u1 = *(const f16x8*)(h1 + (size_t)s1 * D_HID + hl * 8);
            f16x8 u2 = *(const f16x8*)(h1 + (size_t)s2 * D_HID + hl * 8);
            f16x8 u3 = *(const f16x8*)(h1 + (size_t)s3 * D_HID + hl * 8);
#pragma unroll
            for (int j = 0; j < 8; ++j)
                a[j] += (float)u0[j] * w0 + (float)u1[j] * w1 +
                        (float)u2[j] * w2 + (float)u3[j] * w3;
        }
        for (; t + 2 < nn; t += 4) {
            int s0 = __shfl(sidx, t), s1 = __shfl(sidx, t + 2);
            float w0 = __shfl(wv, t), w1 = __shfl(wv, t + 2);
            f16x8 u0 = *(const f16x8*)(h1 + (size_t)s0 * D_HID + hl * 8);
            f16x8 u1 = *(const f16x8*)(h1 + (size_t)s1 * D_HID + hl * 8);
#pragma unroll
            for (int j = 0; j < 8; ++j)
                a[j] += (float)u0[j] * w0 + (float)u1[j] * w1;
        }
        if (t < nn) {
            int s0 = __shfl(sidx, t);
            float w0 = __shfl(wv, t);
            f16x8 u0 = *(const f16x8*)(h1 + (size_t)s0 * D_HID + hl * 8);
#pragma unroll
            for (int j = 0; j < 8; ++j) a[j] += (float)u0[j] * w0;
        }
    }

#pragma unroll
    for (int j = 0; j < 8; ++j) a[j] += __shfl_xor(a[j], 32);

    float wself = di * di;
    float4 b_lo = *(const float4*)(b1 + hl * 8);
    float4 b_hi = *(const float4*)(b1 + hl * 8 + 4);
    f16x8 o;
    o[0] = (f16)fmaxf(a[0] + (float)selfv[0] * wself + b_lo.x, 0.0f);
    o[1] = (f16)fmaxf(a[1] + (float)selfv[1] * wself + b_lo.y, 0.0f);
    o[2] = (f16)fmaxf(a[2] + (float)selfv[2] * wself + b_lo.z, 0.0f);
    o[3] = (f16)fmaxf(a[3] + (float)selfv[3] * wself + b_lo.w, 0.0f);
    o[4] = (f16)fmaxf(a[4] + (float)selfv[4] * wself + b_hi.x, 0.0f);
    o[5] = (f16)fmaxf(a[5] + (float)selfv[5] * wself + b_hi.y, 0.0f);
    o[6] = (f16)fmaxf(a[6] + (float)selfv[6] * wself + b_hi.z, 0.0f);
    o[7] = (f16)fmaxf(a[7] + (float)selfv[7] * wself + b_hi.w, 0.0f);

    if (half == 0) {
        size_t idx = ((size_t)(node >> 4) * 8 + (hl >> 2)) * 512 + (hl & 3) * 128 + (node & 15) * 8;
        *(f16x8*)(hp + idx) = o;
    }
}

// ---------------- aggregation 2: out = log_softmax(Ahat*g + b2) -----------

__global__ __launch_bounds__(256) void k_agg2(const f16* __restrict__ g,
                                              const int* __restrict__ rowptr,
                                              const int* __restrict__ col,
                                              const float* __restrict__ dinv,
                                              const float* __restrict__ b2,
                                              float* __restrict__ out) {
    int node = blockIdx.x * 4 + (threadIdx.x >> 6);
    int lane = threadIdx.x & 63;
    float di = dinv[node];
    bool act = lane < D_OUT_PAD;
    float acc = act ? (float)g[(size_t)node * D_OUT_PAD + lane] * di * di : 0.0f;

    int e0 = rowptr[node], e1 = rowptr[node + 1];
    for (int base = e0; base < e1; base += 64) {
        int nn = min(64, e1 - base);
        int sidx = 0; float wv = 0.0f;
        if (lane < nn) {
            int s = col[base + lane];
            sidx = s;
            wv = dinv[s] * di;
        }
        int k = 0;
        for (; k + 8 <= nn; k += 8) {
            int s0 = __shfl(sidx, k),     s1 = __shfl(sidx, k + 1);
            int s2 = __shfl(sidx, k + 2), s3 = __shfl(sidx, k + 3);
            int s4 = __shfl(sidx, k + 4), s5 = __shfl(sidx, k + 5);
            int s6 = __shfl(sidx, k + 6), s7 = __shfl(sidx, k + 7);
            float w0 = __shfl(wv, k),     w1 = __shfl(wv, k + 1);
            float w2 = __shfl(wv, k + 2), w3 = __shfl(wv, k + 3);
            float w4 = __shfl(wv, k + 4), w5 = __shfl(wv, k + 5);
            float w6 = __shfl(wv, k + 6), w7 = __shfl(wv, k + 7);
            if (act) {
                float u0 = (float)g[(size_t)s0 * D_OUT_PAD + lane];
                float u1 = (float)g[(size_t)s1 * D_OUT_PAD + lane];
                float u2 = (float)g[(size_t)s2 * D_OUT_PAD + lane];
                float u3 = (float)g[(size_t)s3 * D_OUT_PAD + lane];
                float u4 = (float)g[(size_t)s4 * D_OUT_PAD + lane];
                float u5 = (float)g[(size_t)s5 * D_OUT_PAD + lane];
                float u6 = (float)g[(size_t)s6 * D_OUT_PAD + lane];
                float u7 = (float)g[(size_t)s7 * D_OUT_PAD + lane];
                acc += u0 * w0 + u1 * w1 + u2 * w2 + u3 * w3 +
                       u4 * w4 + u5 * w5 + u6 * w6 + u7 * w7;
            }
        }
        for (; k < nn; ++k) {
            int s0 = __shfl(sidx, k);
            float w0 = __shfl(wv, k);
            if (act) acc += (float)g[(size_t)s0 * D_OUT_PAD + lane] * w0;
        }
    }

    float z = (lane < D_OUT) ? acc + b2[lane] : -3.0e38f;
    float mx = z;
#pragma unroll
    for (int off = 32; off >= 1; off >>= 1) mx = fmaxf(mx, __shfl_xor(mx, off));
    float ex = (lane < D_OUT) ? expf(z - mx) : 0.0f;
    float sum = ex;
#pragma unroll
    for (int off = 32; off >= 1; off >>= 1) sum += __shfl_xor(sum, off);
    if (lane < D_OUT) out[(size_t)node * D_OUT + lane] = z - mx - logf(sum);
}

// ---------------- launcher ----------------

extern "C" void kernel_launch(void* const* d_in, const int* in_sizes, int n_in,
                              void* d_out, int out_size, void* d_ws, size_t ws_size,
                              hipStream_t stream) {
    const float* x  = (const float*)d_in[0];
    const int*   ei = (const int*)d_in[1];
    const float* W1 = (const float*)d_in[2];
    const float* b1 = (const float*)d_in[3];
    const float* W2 = (const float*)d_in[4];
    const float* b2 = (const float*)d_in[5];
    float* out = (float*)d_out;

    char* ws = (char*)d_ws;
    int*   degi   = (int*)(ws + 0);              // 160,000 (deg)
    int*   cursor = (int*)(ws + 160000);         // 160,000
    float* dinv   = (float*)(ws + 320000);       // 160,000
    int*   rowptr = (int*)(ws + 480000);         // 160,256 (40001 ints)
    int*   col    = (int*)(ws + 640256);         // 2,560,000
    f16*   w1p    = (f16*)(ws + 3200256);        // 262,144
    f16*   w2p    = (f16*)(ws + 3462400);        // 24,576
    f16*   h1     = (f16*)(ws + 3486976);        // 20,480,000
    f16*   hpk    = (f16*)(ws + 23966976);       // 20,480,000 (packed A, GEMM2)
    f16*   g      = (f16*)(ws + 44446976);       // 3,840,000
    // total 48,286,976 bytes

    k_init<<<383, 256, 0, stream>>>(W1, W2, w1p, w2p, degi);
    k_degree<<<2500, 256, 0, stream>>>(ei, degi);
    k_scan<<<1, 1024, 0, stream>>>(degi, rowptr, dinv);
    k_fill<<<2500, 256, 0, stream>>>(ei, rowptr, cursor, col);

    k_gemm1<<<625, 512, 0, stream>>>(x, w1p, h1);
    k_agg1<<<10000, 256, 0, stream>>>(h1, rowptr, col, dinv, b1, hpk);
    k_gemm2<<<157, 256, 0, stream>>>(hpk, w2p, g);
    k_agg2<<<10000, 256, 0, stream>>>(g, rowptr, col, dinv, b2, out);
}